// Round 16
// baseline (176.739 us; speedup 1.0000x reference)
//
#include <hip/hip_runtime.h>
#include <stdint.h>

typedef __bf16 bf16x8  __attribute__((ext_vector_type(8)));
typedef float  f32x4   __attribute__((ext_vector_type(4)));

#define LOG2E    1.44269504088896340736f
#define SM_SCALE 0.03125f   /* 1/sqrt(1024) */

typedef __attribute__((address_space(1))) const uint32_t gau32;
typedef __attribute__((address_space(3))) uint32_t       lau32;
#define GLD16(g, l) __builtin_amdgcn_global_load_lds((gau32*)(g), (lau32*)(l), 16, 0, 0)

__device__ __forceinline__ uint32_t f2bf(float f) {
  uint32_t u = __builtin_bit_cast(uint32_t, f);
  u += 0x7FFFu + ((u >> 16) & 1u);   // RNE
  return u >> 16;
}
__device__ __forceinline__ uint32_t pk2(float a, float b) {
  return f2bf(a) | (f2bf(b) << 16);
}
__device__ __forceinline__ uint4 pack8(float4 a, float4 b) {
  uint4 r;
  r.x = pk2(a.x, a.y); r.y = pk2(a.z, a.w);
  r.z = pk2(b.x, b.y); r.w = pk2(b.z, b.w);
  return r;
}

// ================= combined prepass (verified r7-r15; at HBM roofline) =================
__global__ __launch_bounds__(256)
void prep_comb(const float* __restrict__ x, uint16_t* __restrict__ vt,
               uint16_t* __restrict__ xf) {
  __shared__ char tl[64 * 144];
  const int t    = threadIdx.x;
  const int blk  = blockIdx.x;
  const int dc   = blk & 15;          // 64-d chunk
  const int kb   = (blk >> 4) & 7;    // 64-key chunk
  const int prob = blk >> 7;          // 0..63
  const int b  = prob >> 4, off = (prob >> 2) & 3, gs = prob & 3;

  const int key = t >> 2, dq = t & 3;
  const float* src = x + ((size_t)(b * 8192 + gs * 2048 + (kb * 64 + key) * 4 + off)) * 1024
                     + dc * 64 + dq * 16;
  float4 f0 = *(const float4*)(src);
  float4 f1 = *(const float4*)(src + 4);
  float4 f2 = *(const float4*)(src + 8);
  float4 f3 = *(const float4*)(src + 12);
  const int swz = (key & 7) << 4;
  *(uint4*)(tl + key * 144 + ((dq * 32) ^ swz))      = pack8(f0, f1);
  *(uint4*)(tl + key * 144 + ((dq * 32 + 16) ^ swz)) = pack8(f2, f3);
  __syncthreads();
  // vt (transposed)
  {
    const int d = t >> 2, kq = t & 3;
    uint32_t w[8];
#pragma unroll
    for (int i = 0; i < 8; ++i) {
      int k0 = kq * 16 + 2 * i, k1 = k0 + 1;
      uint32_t a  = *(const uint16_t*)(tl + k0 * 144 + ((2 * d) ^ ((k0 & 7) << 4)));
      uint32_t bb = *(const uint16_t*)(tl + k1 * 144 + ((2 * d) ^ ((k1 & 7) << 4)));
      w[i] = a | (bb << 16);
    }
    uint16_t* dst = vt + ((size_t)(prob * 1024 + dc * 64 + d)) * 512 + kb * 64 + kq * 16;
    *(uint4*)(dst)     = *(uint4*)&w[0];
    *(uint4*)(dst + 8) = *(uint4*)&w[4];
  }
  // xf (fragment-major)
  {
    const int row = t >> 2, p = t & 3;
    const int dcl = p >> 1;
    const int dq8b = (p & 1) * 2;
    const int swz2 = (row & 7) << 4;
    char* fbase = (char*)xf +
        (((size_t)(prob * 32 + kb * 4 + (row >> 4)) * 32) + (dc * 2 + dcl)) * 1024;
#pragma unroll
    for (int i = 0; i < 2; ++i) {
      const int dq8 = dq8b + i;
      uint4 w = *(const uint4*)(tl + row * 144 + ((dcl * 64 + dq8 * 16) ^ swz2));
      *(uint4*)(fbase + ((row & 15) + 16 * dq8) * 16) = w;
    }
  }
}

// ========== main kernel v14: r15 + A-reg-depth-2 (ph1) + V-reg-depth-2 (ph3) ==========
// LDS: Q-half [0,131072): [dcl 0..15][qt 0..7][1024B] (staged twice)
//      P' fragment-major [qt 0..7][ks 0..15][lane][16B] aliases [0,131072)
//      red0 @131072, red1 @139264. Total 144 KB, 1 block/CU.
#define RD_0 131072
#define RD_1 139264
#define LDSD_BYTES 147456

__global__ __launch_bounds__(512, 2)   // 256-reg budget; ph1 ~212 live, ph3 ~190 live
void dilattn13(const char* __restrict__ xf, const char* __restrict__ vt,
               float* __restrict__ out) {
  extern __shared__ char smem[];

  const int tid  = threadIdx.x;
  const int lane = tid & 63;
  const int wid  = tid >> 6;          // 0..7
  const int h    = lane >> 4;
  const int l15  = lane & 15;
  const int lane16 = lane * 16;

  const int blk  = blockIdx.x;        // 256 blocks; same-prob q-blocks share XCD class
  const int jj   = blk >> 3;          // 0..31
  const int prob = ((blk & 7) << 3) + (jj >> 2);
  const int q0   = (jj & 3) * 128;
  const int b    = prob >> 4;
  const int off  = (prob >> 2) & 3;
  const int gs   = prob & 3;

  const char* xfp = xf + (size_t)prob * 1048576;
  const int qtile0 = q0 >> 4;
  const char* xfA = xfp + (size_t)(4 * wid) * 32768 + lane16;   // wave's 4 ktiles = 64 keys

  f32x4 S[4][8];
#pragma unroll
  for (int i = 0; i < 4; ++i)
#pragma unroll
    for (int j = 0; j < 8; ++j) S[i][j] = (f32x4){0.f, 0.f, 0.f, 0.f};

#define LOADA13(dca, A) do {                                      \
    A[0] = *(const bf16x8*)(xfA + (dca) * 1024);                  \
    A[1] = *(const bf16x8*)(xfA + 32768 + (dca) * 1024);          \
    A[2] = *(const bf16x8*)(xfA + 65536 + (dca) * 1024);          \
    A[3] = *(const bf16x8*)(xfA + 98304 + (dca) * 1024); } while (0)

  // ===== phase 1: S = K Q^T; Q staged in two halves; A register depth-2 =====
  bf16x8 aC[4], aN[4];
  LOADA13(0, aC);                                     // prefetch chunk 0 (global, no LDS dep)
#pragma unroll 1
  for (int half = 0; half < 2; ++half) {
#pragma unroll
    for (int i = 0; i < 16; ++i) {                    // stage 128 KB: 8 waves x 16 cells
      const int c_ = wid * 16 + i;
      const int dcl = c_ >> 3, qt = c_ & 7;
      GLD16(xfp + ((size_t)(qtile0 + qt) * 32 + (half * 16 + dcl)) * 1024 + lane16,
            smem + dcl * 8192 + qt * 1024);
    }
    __syncthreads();                                  // half staged
#pragma unroll
    for (int dc = 0; dc < 16; ++dc) {
      const int dca = half * 16 + dc;
      if (dca < 31) LOADA13(dca + 1, aN);             // prefetch next chunk's A-frags
      const char* qb = smem + dc * 8192 + lane16;
      bf16x8 bq[8];
#pragma unroll
      for (int qt = 0; qt < 8; ++qt)
        bq[qt] = *(const bf16x8*)(qb + qt * 1024);
      __builtin_amdgcn_s_setprio(1);
#pragma unroll
      for (int qt = 0; qt < 8; ++qt) {
        S[0][qt] = __builtin_amdgcn_mfma_f32_16x16x32_bf16(aC[0], bq[qt], S[0][qt], 0, 0, 0);
        S[1][qt] = __builtin_amdgcn_mfma_f32_16x16x32_bf16(aC[1], bq[qt], S[1][qt], 0, 0, 0);
        S[2][qt] = __builtin_amdgcn_mfma_f32_16x16x32_bf16(aC[2], bq[qt], S[2][qt], 0, 0, 0);
        S[3][qt] = __builtin_amdgcn_mfma_f32_16x16x32_bf16(aC[3], bq[qt], S[3][qt], 0, 0, 0);
      }
      __builtin_amdgcn_s_setprio(0);
      if (dca < 31) {
#pragma unroll
        for (int kt = 0; kt < 4; ++kt) aC[kt] = aN[kt];
      }
    }
    __syncthreads();                                  // all waves done reading this half
  }

  // ===== phase 2: exact softmax over 512 keys for 128 q-rows (r15-verified) =====
  float mq[8], sq[8], rinv[8];
#pragma unroll
  for (int qt = 0; qt < 8; ++qt) {
    float m = S[0][qt][0];
#pragma unroll
    for (int kt = 0; kt < 4; ++kt)
#pragma unroll
      for (int r = 0; r < 4; ++r) m = fmaxf(m, S[kt][qt][r]);
    m = fmaxf(m, __shfl_xor(m, 16, 64));
    m = fmaxf(m, __shfl_xor(m, 32, 64));
    mq[qt] = m;
  }
  if (h == 0) {
#pragma unroll
    for (int qt = 0; qt < 8; ++qt)
      *(float*)(smem + RD_0 + (wid * 128 + qt * 16 + l15) * 4) = mq[qt];
  }
  __syncthreads();                                    // B1
#pragma unroll
  for (int qt = 0; qt < 8; ++qt) {
    float m = -3e38f;
#pragma unroll
    for (int w = 0; w < 8; ++w)
      m = fmaxf(m, *(const float*)(smem + RD_0 + (w * 128 + qt * 16 + l15) * 4));
    mq[qt] = m * SM_SCALE;
    sq[qt] = 0.f;
  }
#pragma unroll
  for (int kt = 0; kt < 4; ++kt)
#pragma unroll
    for (int qt = 0; qt < 8; ++qt)
#pragma unroll
      for (int r = 0; r < 4; ++r) {
        float v = exp2f((S[kt][qt][r] * SM_SCALE - mq[qt]) * LOG2E);
        S[kt][qt][r] = v;
        sq[qt] += v;
      }
#pragma unroll
  for (int qt = 0; qt < 8; ++qt) {
    sq[qt] += __shfl_xor(sq[qt], 16, 64);
    sq[qt] += __shfl_xor(sq[qt], 32, 64);
  }
  if (h == 0) {
#pragma unroll
    for (int qt = 0; qt < 8; ++qt)
      *(float*)(smem + RD_1 + (wid * 128 + qt * 16 + l15) * 4) = sq[qt];
  }
  __syncthreads();                                    // B2 (Q-frag reads all done)
#pragma unroll
  for (int qt = 0; qt < 8; ++qt) {
    float l = 0.f;
#pragma unroll
    for (int w = 0; w < 8; ++w)
      l += *(const float*)(smem + RD_1 + (w * 128 + qt * 16 + l15) * 4);
    rinv[qt] = 0.25f / l;                            // fold denom and /r=4 into P
  }
  // P' write, fragment-major (r15-verified byte layout)
#pragma unroll
  for (int kt = 0; kt < 4; ++kt)
#pragma unroll
    for (int qt = 0; qt < 8; ++qt) {
      uint2 w2;
      w2.x = pk2(S[kt][qt][0] * rinv[qt], S[kt][qt][1] * rinv[qt]);
      w2.y = pk2(S[kt][qt][2] * rinv[qt], S[kt][qt][3] * rinv[qt]);
      *(uint2*)(smem + qt * 16384 + (2 * wid + (kt >> 1)) * 1024 +
                (l15 + 16 * (2 * (kt & 1) + (h >> 1))) * 16 + 8 * (h & 1)) = w2;
    }
  __syncthreads();                                    // B3: P' ready

  // ===== phase 3: O = P V; two 512-d passes; V register depth-2 =====
#pragma unroll 1
  for (int p = 0; p < 2; ++p) {
    const int dbase = p * 512 + 64 * wid;
    f32x4 acc[4][8];
#pragma unroll
    for (int i = 0; i < 4; ++i)
#pragma unroll
      for (int j = 0; j < 8; ++j) acc[i][j] = (f32x4){0.f, 0.f, 0.f, 0.f};

    const char* vtW = vt + (size_t)prob * 1048576 + (size_t)(dbase + l15) * 1024 + 16 * h;
    bf16x8 vc0 = *(const bf16x8*)(vtW);
    bf16x8 vc1 = *(const bf16x8*)(vtW + 16384);
    bf16x8 vc2 = *(const bf16x8*)(vtW + 32768);
    bf16x8 vc3 = *(const bf16x8*)(vtW + 49152);
#pragma unroll 1
    for (int ks = 0; ks < 16; ++ks) {
      bf16x8 vn0, vn1, vn2, vn3;
      if (ks < 15) {
        vn0 = *(const bf16x8*)(vtW + (ks + 1) * 64);
        vn1 = *(const bf16x8*)(vtW + 16384 + (ks + 1) * 64);
        vn2 = *(const bf16x8*)(vtW + 32768 + (ks + 1) * 64);
        vn3 = *(const bf16x8*)(vtW + 49152 + (ks + 1) * 64);
      }
      __builtin_amdgcn_s_setprio(1);
#pragma unroll
      for (int qp = 0; qp < 4; ++qp) {
        bf16x8 pa0 = *(const bf16x8*)(smem + (2 * qp) * 16384 + ks * 1024 + lane16);
        bf16x8 pa1 = *(const bf16x8*)(smem + (2 * qp + 1) * 16384 + ks * 1024 + lane16);
        acc[0][2 * qp]     = __builtin_amdgcn_mfma_f32_16x16x32_bf16(pa0, vc0, acc[0][2 * qp], 0, 0, 0);
        acc[1][2 * qp]     = __builtin_amdgcn_mfma_f32_16x16x32_bf16(pa0, vc1, acc[1][2 * qp], 0, 0, 0);
        acc[2][2 * qp]     = __builtin_amdgcn_mfma_f32_16x16x32_bf16(pa0, vc2, acc[2][2 * qp], 0, 0, 0);
        acc[3][2 * qp]     = __builtin_amdgcn_mfma_f32_16x16x32_bf16(pa0, vc3, acc[3][2 * qp], 0, 0, 0);
        acc[0][2 * qp + 1] = __builtin_amdgcn_mfma_f32_16x16x32_bf16(pa1, vc0, acc[0][2 * qp + 1], 0, 0, 0);
        acc[1][2 * qp + 1] = __builtin_amdgcn_mfma_f32_16x16x32_bf16(pa1, vc1, acc[1][2 * qp + 1], 0, 0, 0);
        acc[2][2 * qp + 1] = __builtin_amdgcn_mfma_f32_16x16x32_bf16(pa1, vc2, acc[2][2 * qp + 1], 0, 0, 0);
        acc[3][2 * qp + 1] = __builtin_amdgcn_mfma_f32_16x16x32_bf16(pa1, vc3, acc[3][2 * qp + 1], 0, 0, 0);
      }
      __builtin_amdgcn_s_setprio(0);
      if (ks < 15) { vc0 = vn0; vc1 = vn1; vc2 = vn2; vc3 = vn3; }
    }
    float* outW = out + ((size_t)(b * 8192 + gs * 2048 + (q0 + 4 * h) * 4 + off)) * 1024
                  + dbase + l15;
#pragma unroll
    for (int cd = 0; cd < 4; ++cd)
#pragma unroll
      for (int qt = 0; qt < 8; ++qt)
#pragma unroll
        for (int r = 0; r < 4; ++r)
          outW[(size_t)((16 * qt + r) * 4) * 1024 + cd * 16] = acc[cd][qt][r];
  }
#undef LOADA13
}

// ======================================================================
// ============ fallback path (round-4, verified PASS) ==================
#define KP_OFF 0
#define Q_OFF  65536
#define RED0   65536
#define RED1   67584
#define LDS_BYTES 73728

__global__ __launch_bounds__(256)
void vt_prepass(const float* __restrict__ x, uint16_t* __restrict__ vt) {
  __shared__ char tl[64 * 144];
  const int t    = threadIdx.x;
  const int blk  = blockIdx.x;
  const int dc   = blk & 15;
  const int kb   = (blk >> 4) & 7;
  const int prob = blk >> 7;
  const int b  = prob >> 4, off = (prob >> 2) & 3, gs = prob & 3;

  const int key = t >> 2, dq = t & 3;
  const float* src = x + ((size_t)(b * 8192 + gs * 2048 + (kb * 64 + key) * 4 + off)) * 1024
                     + dc * 64 + dq * 16;
  float4 f0 = *(const float4*)(src);
  float4 f1 = *(const float4*)(src + 4);
  float4 f2 = *(const float4*)(src + 8);
  float4 f3 = *(const float4*)(src + 12);
  const int swz = (key & 7) << 4;
  *(uint4*)(tl + key * 144 + ((dq * 32) ^ swz))      = pack8(f0, f1);
  *(uint4*)(tl + key * 144 + ((dq * 32 + 16) ^ swz)) = pack8(f2, f3);
  __syncthreads();
  const int d = t >> 2, kq = t & 3;
  uint32_t w[8];
#pragma unroll
  for (int i = 0; i < 8; ++i) {
    int k0 = kq * 16 + 2 * i, k1 = k0 + 1;
    uint32_t a  = *(const uint16_t*)(tl + k0 * 144 + ((2 * d) ^ ((k0 & 7) << 4)));
    uint32_t bb = *(const uint16_t*)(tl + k1 * 144 + ((2 * d) ^ ((k1 & 7) << 4)));
    w[i] = a | (bb << 16);
  }
  uint16_t* dst = vt + ((size_t)(prob * 1024 + dc * 64 + d)) * 512 + kb * 64 + kq * 16;
  *(uint4*)(dst)     = *(uint4*)&w[0];
  *(uint4*)(dst + 8) = *(uint4*)&w[4];
}

template <int USE_VT>
__global__ __launch_bounds__(512, 2)
void dilattn2(const float* __restrict__ x, const uint16_t* __restrict__ vt,
              float* __restrict__ out) {
  extern __shared__ char smem[];

  const int tid  = threadIdx.x;
  const int lane = tid & 63;
  const int wid  = tid >> 6;
  const int h    = lane >> 4;
  const int l15  = lane & 15;
  const int psw  = (l15 & 7) << 4;

  const int blk  = blockIdx.x;
  const int prob = blk >> 3;
  const int q0   = (blk & 7) * 64;
  const int b    = prob >> 4;
  const int off  = (prob >> 2) & 3;
  const int gs   = prob & 3;

  const float* xb = x + (size_t)b * (8192u * 1024u);

  const int srow = tid >> 3;
  const int sg   = tid & 7;
  const float* gK = xb + (size_t)(gs * 2048 + srow * 4 + off) * 1024 + sg * 8;
  const float* gQ = xb + (size_t)(gs * 2048 + (q0 + srow) * 4 + off) * 1024 + sg * 8;
  const int kWr = srow * 128 + ((sg * 16) ^ ((srow & 7) << 4));
  const int qWr = Q_OFF + kWr;

  const int akR = (64 * wid + l15) * 128;
  const int bqR = Q_OFF + l15 * 128;
  const int fb0 = (16 * h) ^ psw;

  f32x4 S[4][4];
#pragma unroll
  for (int i = 0; i < 4; ++i)
#pragma unroll
    for (int j = 0; j < 4; ++j) S[i][j] = (f32x4){0.f, 0.f, 0.f, 0.f};

  float4 kp[16], qp[2];
#pragma unroll
  for (int j = 0; j < 8; ++j) {
    const float* p = gK + (size_t)j * 262144;
    kp[2 * j]     = *(const float4*)(p);
    kp[2 * j + 1] = *(const float4*)(p + 4);
  }
  qp[0] = *(const float4*)(gQ);
  qp[1] = *(const float4*)(gQ + 4);

#pragma unroll 1
  for (int dc = 0; dc < 16; ++dc) {
#pragma unroll
    for (int j = 0; j < 8; ++j)
      *(uint4*)(smem + KP_OFF + kWr + j * 8192) = pack8(kp[2 * j], kp[2 * j + 1]);
    *(uint4*)(smem + qWr) = pack8(qp[0], qp[1]);
    if (dc < 15) {
      const int doff = (dc + 1) * 64;
#pragma unroll
      for (int j = 0; j < 8; ++j) {
        const float* p = gK + (size_t)j * 262144 + doff;
        kp[2 * j]     = *(const float4*)(p);
        kp[2 * j + 1] = *(const float4*)(p + 4);
      }
      qp[0] = *(const float4*)(gQ + doff);
      qp[1] = *(const float4*)(gQ + doff + 4);
    }
    __syncthreads();
#pragma unroll
    for (int s = 0; s < 2; ++s) {
      const int fb = fb0 ^ (s << 6);
      bf16x8 aK[4], bq[4];
#pragma unroll
      for (int kt = 0; kt < 4; ++kt)
        aK[kt] = *(const bf16x8*)(smem + akR + kt * 2048 + fb);
#pragma unroll
      for (int qt = 0; qt < 4; ++qt)
        bq[qt] = *(const bf16x8*)(smem + bqR + qt * 2048 + fb);
#pragma unroll
      for (int kt = 0; kt < 4; ++kt)
#pragma unroll
        for (int qt = 0; qt < 4; ++qt)
          S[kt][qt] = __builtin_amdgcn_mfma_f32_16x16x32_bf16(aK[kt], bq[qt], S[kt][qt], 0, 0, 0);
    }
    __syncthreads();
  }

  float mq[4], sq[4], rinv[4];
#pragma unroll
  for (int qt = 0; qt < 4; ++qt) {
    float m = S[0][qt][0];
#pragma unroll
    for (int kt = 0; kt < 4; ++kt)
#pragma unroll
      for (int r = 0; r < 4; ++r) m = fmaxf(m, S[kt][qt][r]);
    m = fmaxf(m, __shfl_xor(m, 16, 64));
    m = fmaxf(m, __shfl_xor(m, 32, 64));
    mq[qt] = m;
  }
  if (h == 0) {
#pragma unroll
    for (int qt = 0; qt < 4; ++qt)
      *(float*)(smem + RED0 + (wid * 64 + 16 * qt + l15) * 4) = mq[qt];
  }
  __syncthreads();
#pragma unroll
  for (int qt = 0; qt < 4; ++qt) {
    float m = -3e38f;
#pragma unroll
    for (int w = 0; w < 8; ++w)
      m = fmaxf(m, *(const float*)(smem + RED0 + (w * 64 + 16 * qt + l15) * 4));
    mq[qt] = m * SM_SCALE;
    sq[qt] = 0.f;
  }
#pragma unroll
  for (int kt = 0; kt < 4; ++kt)
#pragma unroll
    for (int qt = 0; qt < 4; ++qt)
#pragma unroll
      for (int r = 0; r < 4; ++r) {
        float v = exp2f((S[kt][qt][r] * SM_SCALE - mq[qt]) * LOG2E);
        S[kt][qt][r] = v;
        sq[qt] += v;
      }
#pragma unroll
  for (int qt = 0; qt < 4; ++qt) {
    sq[qt] += __shfl_xor(sq[qt], 16, 64);
    sq[qt] += __shfl_xor(sq[qt], 32, 64);
  }
  if (h == 0) {
#pragma unroll
    for (int qt = 0; qt < 4; ++qt)
      *(float*)(smem + RED1 + (wid * 64 + 16 * qt + l15) * 4) = sq[qt];
  }
  __syncthreads();
#pragma unroll
  for (int qt = 0; qt < 4; ++qt) {
    float l = 0.f;
#pragma unroll
    for (int w = 0; w < 8; ++w)
      l += *(const float*)(smem + RED1 + (w * 64 + 16 * qt + l15) * 4);
    rinv[qt] = 0.25f / l;
  }
#pragma unroll
  for (int kt = 0; kt < 4; ++kt)
#pragma unroll
    for (int qt = 0; qt < 4; ++qt) {
      uint2 w2;
      w2.x = pk2(S[kt][qt][0] * rinv[qt], S[kt][qt][1] * rinv[qt]);
      w2.y = pk2(S[kt][qt][2] * rinv[qt], S[kt][qt][3] * rinv[qt]);
      *(uint2*)(smem + KP_OFF + (16 * qt + l15) * 1024 +
                ((128 * wid + 32 * kt + 8 * h) ^ psw)) = w2;
    }
  __syncthreads();

  f32x4 acc[8][4];
#pragma unroll
  for (int i = 0; i < 8; ++i)
#pragma unroll
    for (int j = 0; j < 4; ++j) acc[i][j] = (f32x4){0.f, 0.f, 0.f, 0.f};

  const uint16_t* vtW = nullptr;
  if constexpr (USE_VT)
    vtW = vt + ((size_t)(prob * 1024 + 128 * wid + l15)) * 512 + 8 * h;

#pragma unroll 1
  for (int ks = 0; ks < 16; ++ks) {
    bf16x8 pa[4];
#pragma unroll
    for (int qt = 0; qt < 4; ++qt)
      pa[qt] = *(const bf16x8*)(smem + KP_OFF + (16 * qt + l15) * 1024 +
                                ((64 * ks + 16 * h) ^ psw));
#pragma unroll
    for (int cd = 0; cd < 8; ++cd) {
      bf16x8 v;
      if constexpr (USE_VT) {
        v = *(const bf16x8*)(vtW + (size_t)((cd >> 2) * 64 + (cd & 3) * 16) * 512 + 32 * ks);
      } else {
        const int d = 128 * wid + (cd >> 2) * 64 + (cd & 3) * 16 + l15;
        union { bf16x8 v; uint16_t u[8]; } a0;
#pragma unroll
        for (int jj = 0; jj < 8; ++jj) {
          int key = 32 * ks + 8 * h + jj;
          a0.u[jj] = (uint16_t)f2bf(xb[(size_t)(gs * 2048 + key * 4 + off) * 1024 + d]);
        }
        v = a0.v;
      }
#pragma unroll
      for (int qt = 0; qt < 4; ++qt)
        acc[cd][qt] = __builtin_amdgcn_mfma_f32_16x16x32_bf16(pa[qt], v, acc[cd][qt], 0, 0, 0);
    }
  }

#pragma unroll
  for (int cd = 0; cd < 8; ++cd) {
    const int d = 128 * wid + (cd >> 2) * 64 + (cd & 3) * 16 + l15;
#pragma unroll
    for (int qt = 0; qt < 4; ++qt)
#pragma unroll
      for (int r = 0; r < 4; ++r) {
        const int qq = q0 + 16 * qt + 4 * h + r;
        out[((size_t)(b * 8192 + gs * 2048 + qq * 4 + off)) * 1024 + d] = acc[cd][qt][r];
      }
  }
}

extern "C" void kernel_launch(void* const* d_in, const int* in_sizes, int n_in,
                              void* d_out, int out_size, void* d_ws, size_t ws_size,
                              hipStream_t stream) {
  const float* x = (const float*)d_in[0];
  float* out = (float*)d_out;
  (void)in_sizes; (void)n_in; (void)out_size;
  const size_t vt_bytes = 64ull * 1024 * 512 * 2;   // 64 MiB
  const size_t xf_bytes = 64ull * 1024 * 1024;      // 64 MiB
  if (ws_size >= vt_bytes + xf_bytes) {
    uint16_t* vtp = (uint16_t*)d_ws;
    uint16_t* xfp = (uint16_t*)((char*)d_ws + vt_bytes);
    hipFuncSetAttribute(reinterpret_cast<const void*>(dilattn13),
                        hipFuncAttributeMaxDynamicSharedMemorySize, LDSD_BYTES);
    prep_comb<<<8192, 256, 0, stream>>>(x, vtp, xfp);
    dilattn13<<<256, 512, LDSD_BYTES, stream>>>((const char*)xfp, (const char*)vtp, out);
  } else if (ws_size >= vt_bytes) {
    uint16_t* vtp = (uint16_t*)d_ws;
    hipFuncSetAttribute(reinterpret_cast<const void*>(dilattn2<1>),
                        hipFuncAttributeMaxDynamicSharedMemorySize, LDS_BYTES);
    vt_prepass<<<8192, 256, 0, stream>>>(x, vtp);
    dilattn2<1><<<512, 512, LDS_BYTES, stream>>>(x, vtp, out);
  } else {
    hipFuncSetAttribute(reinterpret_cast<const void*>(dilattn2<0>),
                        hipFuncAttributeMaxDynamicSharedMemorySize, LDS_BYTES);
    dilattn2<0><<<512, 512, LDS_BYTES, stream>>>(x, nullptr, out);
  }
}

// Round 17
// 164.125 us; speedup vs baseline: 1.0769x; 1.0769x over previous
//
#include <hip/hip_runtime.h>
#include <stdint.h>

typedef __bf16 bf16x8  __attribute__((ext_vector_type(8)));
typedef float  f32x4   __attribute__((ext_vector_type(4)));

#define LOG2E    1.44269504088896340736f
#define SM_SCALE 0.03125f   /* 1/sqrt(1024) */

typedef __attribute__((address_space(1))) const uint32_t gau32;
typedef __attribute__((address_space(3))) uint32_t       lau32;
#define GLD16(g, l) __builtin_amdgcn_global_load_lds((gau32*)(g), (lau32*)(l), 16, 0, 0)

__device__ __forceinline__ uint32_t f2bf(float f) {
  uint32_t u = __builtin_bit_cast(uint32_t, f);
  u += 0x7FFFu + ((u >> 16) & 1u);   // RNE
  return u >> 16;
}
__device__ __forceinline__ uint32_t pk2(float a, float b) {
  return f2bf(a) | (f2bf(b) << 16);
}
__device__ __forceinline__ uint4 pack8(float4 a, float4 b) {
  uint4 r;
  r.x = pk2(a.x, a.y); r.y = pk2(a.z, a.w);
  r.z = pk2(b.x, b.y); r.w = pk2(b.z, b.w);
  return r;
}

// ================= combined prepass (verified r7-r15; at HBM roofline) =================
__global__ __launch_bounds__(256)
void prep_comb(const float* __restrict__ x, uint16_t* __restrict__ vt,
               uint16_t* __restrict__ xf) {
  __shared__ char tl[64 * 144];
  const int t    = threadIdx.x;
  const int blk  = blockIdx.x;
  const int dc   = blk & 15;          // 64-d chunk
  const int kb   = (blk >> 4) & 7;    // 64-key chunk
  const int prob = blk >> 7;          // 0..63
  const int b  = prob >> 4, off = (prob >> 2) & 3, gs = prob & 3;

  const int key = t >> 2, dq = t & 3;
  const float* src = x + ((size_t)(b * 8192 + gs * 2048 + (kb * 64 + key) * 4 + off)) * 1024
                     + dc * 64 + dq * 16;
  float4 f0 = *(const float4*)(src);
  float4 f1 = *(const float4*)(src + 4);
  float4 f2 = *(const float4*)(src + 8);
  float4 f3 = *(const float4*)(src + 12);
  const int swz = (key & 7) << 4;
  *(uint4*)(tl + key * 144 + ((dq * 32) ^ swz))      = pack8(f0, f1);
  *(uint4*)(tl + key * 144 + ((dq * 32 + 16) ^ swz)) = pack8(f2, f3);
  __syncthreads();
  // vt (transposed)
  {
    const int d = t >> 2, kq = t & 3;
    uint32_t w[8];
#pragma unroll
    for (int i = 0; i < 8; ++i) {
      int k0 = kq * 16 + 2 * i, k1 = k0 + 1;
      uint32_t a  = *(const uint16_t*)(tl + k0 * 144 + ((2 * d) ^ ((k0 & 7) << 4)));
      uint32_t bb = *(const uint16_t*)(tl + k1 * 144 + ((2 * d) ^ ((k1 & 7) << 4)));
      w[i] = a | (bb << 16);
    }
    uint16_t* dst = vt + ((size_t)(prob * 1024 + dc * 64 + d)) * 512 + kb * 64 + kq * 16;
    *(uint4*)(dst)     = *(uint4*)&w[0];
    *(uint4*)(dst + 8) = *(uint4*)&w[4];
  }
  // xf (fragment-major)
  {
    const int row = t >> 2, p = t & 3;
    const int dcl = p >> 1;
    const int dq8b = (p & 1) * 2;
    const int swz2 = (row & 7) << 4;
    char* fbase = (char*)xf +
        (((size_t)(prob * 32 + kb * 4 + (row >> 4)) * 32) + (dc * 2 + dcl)) * 1024;
#pragma unroll
    for (int i = 0; i < 2; ++i) {
      const int dq8 = dq8b + i;
      uint4 w = *(const uint4*)(tl + row * 144 + ((dcl * 64 + dq8 * 16) ^ swz2));
      *(uint4*)(fbase + ((row & 15) + 16 * dq8) * 16) = w;
    }
  }
}

// ========== main kernel v13 (r15 best-known): 8 waves x 64 keys, 256-reg budget ==========
// LDS: Q-half [0,131072): [dcl 0..15][qt 0..7][1024B] (staged twice)
//      P' fragment-major [qt 0..7][ks 0..15][lane][16B] aliases [0,131072)
//      red0 @131072 (8w x 128q f32 = 4 KB), red1 @139264. Total 144 KB, 1 block/CU.
#define RC_0 131072
#define RC_1 139264
#define LDSC_BYTES 147456

__global__ __launch_bounds__(512, 2)   // 256-reg budget: S[4][8]=128 AGPR fits, no spill
void dilattn12(const char* __restrict__ xf, const char* __restrict__ vt,
               float* __restrict__ out) {
  extern __shared__ char smem[];

  const int tid  = threadIdx.x;
  const int lane = tid & 63;
  const int wid  = tid >> 6;          // 0..7
  const int h    = lane >> 4;
  const int l15  = lane & 15;
  const int lane16 = lane * 16;

  const int blk  = blockIdx.x;        // 256 blocks; same-prob q-blocks share XCD class
  const int jj   = blk >> 3;          // 0..31
  const int prob = ((blk & 7) << 3) + (jj >> 2);
  const int q0   = (jj & 3) * 128;
  const int b    = prob >> 4;
  const int off  = (prob >> 2) & 3;
  const int gs   = prob & 3;

  const char* xfp = xf + (size_t)prob * 1048576;
  const int qtile0 = q0 >> 4;
  const char* xfA = xfp + (size_t)(4 * wid) * 32768 + lane16;   // wave's 4 ktiles = 64 keys

  f32x4 S[4][8];
#pragma unroll
  for (int i = 0; i < 4; ++i)
#pragma unroll
    for (int j = 0; j < 8; ++j) S[i][j] = (f32x4){0.f, 0.f, 0.f, 0.f};

  // ===== phase 1: S = K Q^T; Q (128 rows) staged in two 512-d halves =====
#pragma unroll 1
  for (int half = 0; half < 2; ++half) {
#pragma unroll
    for (int i = 0; i < 16; ++i) {                    // stage 128 KB: 8 waves x 16 cells
      const int c_ = wid * 16 + i;
      const int dcl = c_ >> 3, qt = c_ & 7;
      GLD16(xfp + ((size_t)(qtile0 + qt) * 32 + (half * 16 + dcl)) * 1024 + lane16,
            smem + dcl * 8192 + qt * 1024);
    }
    __syncthreads();                                  // half staged
#pragma unroll
    for (int dc = 0; dc < 16; ++dc) {
      const int dca = half * 16 + dc;
      bf16x8 a0 = *(const bf16x8*)(xfA + dca * 1024);
      bf16x8 a1 = *(const bf16x8*)(xfA + 32768 + dca * 1024);
      bf16x8 a2 = *(const bf16x8*)(xfA + 65536 + dca * 1024);
      bf16x8 a3 = *(const bf16x8*)(xfA + 98304 + dca * 1024);
      const char* qb = smem + dc * 8192 + lane16;
      bf16x8 bq[8];
#pragma unroll
      for (int qt = 0; qt < 8; ++qt)
        bq[qt] = *(const bf16x8*)(qb + qt * 1024);
      __builtin_amdgcn_s_setprio(1);
#pragma unroll
      for (int qt = 0; qt < 8; ++qt) {
        S[0][qt] = __builtin_amdgcn_mfma_f32_16x16x32_bf16(a0, bq[qt], S[0][qt], 0, 0, 0);
        S[1][qt] = __builtin_amdgcn_mfma_f32_16x16x32_bf16(a1, bq[qt], S[1][qt], 0, 0, 0);
        S[2][qt] = __builtin_amdgcn_mfma_f32_16x16x32_bf16(a2, bq[qt], S[2][qt], 0, 0, 0);
        S[3][qt] = __builtin_amdgcn_mfma_f32_16x16x32_bf16(a3, bq[qt], S[3][qt], 0, 0, 0);
      }
      __builtin_amdgcn_s_setprio(0);
    }
    __syncthreads();                                  // all waves done reading this half
  }

  // ===== phase 2: exact softmax over 512 keys for 128 q-rows =====
  float mq[8], sq[8], rinv[8];
#pragma unroll
  for (int qt = 0; qt < 8; ++qt) {
    float m = S[0][qt][0];
#pragma unroll
    for (int kt = 0; kt < 4; ++kt)
#pragma unroll
      for (int r = 0; r < 4; ++r) m = fmaxf(m, S[kt][qt][r]);
    m = fmaxf(m, __shfl_xor(m, 16, 64));
    m = fmaxf(m, __shfl_xor(m, 32, 64));
    mq[qt] = m;
  }
  if (h == 0) {
#pragma unroll
    for (int qt = 0; qt < 8; ++qt)
      *(float*)(smem + RC_0 + (wid * 128 + qt * 16 + l15) * 4) = mq[qt];
  }
  __syncthreads();                                    // B1
#pragma unroll
  for (int qt = 0; qt < 8; ++qt) {
    float m = -3e38f;
#pragma unroll
    for (int w = 0; w < 8; ++w)
      m = fmaxf(m, *(const float*)(smem + RC_0 + (w * 128 + qt * 16 + l15) * 4));
    mq[qt] = m * SM_SCALE;
    sq[qt] = 0.f;
  }
#pragma unroll
  for (int kt = 0; kt < 4; ++kt)
#pragma unroll
    for (int qt = 0; qt < 8; ++qt)
#pragma unroll
      for (int r = 0; r < 4; ++r) {
        float v = exp2f((S[kt][qt][r] * SM_SCALE - mq[qt]) * LOG2E);
        S[kt][qt][r] = v;
        sq[qt] += v;
      }
#pragma unroll
  for (int qt = 0; qt < 8; ++qt) {
    sq[qt] += __shfl_xor(sq[qt], 16, 64);
    sq[qt] += __shfl_xor(sq[qt], 32, 64);
  }
  if (h == 0) {
#pragma unroll
    for (int qt = 0; qt < 8; ++qt)
      *(float*)(smem + RC_1 + (wid * 128 + qt * 16 + l15) * 4) = sq[qt];
  }
  __syncthreads();                                    // B2 (Q-frag reads all done)
#pragma unroll
  for (int qt = 0; qt < 8; ++qt) {
    float l = 0.f;
#pragma unroll
    for (int w = 0; w < 8; ++w)
      l += *(const float*)(smem + RC_1 + (w * 128 + qt * 16 + l15) * 4);
    rinv[qt] = 0.25f / l;                            // fold denom and /r=4 into P
  }
  // P' write, fragment-major (same byte layout as r12):
  // key = 64*wid + 16*kt + 4*h + r -> ks = 2*wid + (kt>>1), half = kt&1
  // slot lane' = l15 + 16*(2*half + (h>>1)); byte 8*(h&1)
#pragma unroll
  for (int kt = 0; kt < 4; ++kt)
#pragma unroll
    for (int qt = 0; qt < 8; ++qt) {
      uint2 w2;
      w2.x = pk2(S[kt][qt][0] * rinv[qt], S[kt][qt][1] * rinv[qt]);
      w2.y = pk2(S[kt][qt][2] * rinv[qt], S[kt][qt][3] * rinv[qt]);
      *(uint2*)(smem + qt * 16384 + (2 * wid + (kt >> 1)) * 1024 +
                (l15 + 16 * (2 * (kt & 1) + (h >> 1))) * 16 + 8 * (h & 1)) = w2;
    }
  __syncthreads();                                    // B3: P' ready

  // ===== phase 3: O = P V; two 512-d passes, wave owns 64-d slice =====
#pragma unroll 1
  for (int p = 0; p < 2; ++p) {
    const int dbase = p * 512 + 64 * wid;
    f32x4 acc[4][8];
#pragma unroll
    for (int i = 0; i < 4; ++i)
#pragma unroll
      for (int j = 0; j < 8; ++j) acc[i][j] = (f32x4){0.f, 0.f, 0.f, 0.f};

    const char* vtW = vt + (size_t)prob * 1048576 + (size_t)(dbase + l15) * 1024 + 16 * h;
#pragma unroll 1
    for (int ks = 0; ks < 16; ++ks) {
      bf16x8 v0 = *(const bf16x8*)(vtW + 0 * 16384 + ks * 64);
      bf16x8 v1 = *(const bf16x8*)(vtW + 1 * 16384 + ks * 64);
      bf16x8 v2 = *(const bf16x8*)(vtW + 2 * 16384 + ks * 64);
      bf16x8 v3 = *(const bf16x8*)(vtW + 3 * 16384 + ks * 64);
      __builtin_amdgcn_s_setprio(1);
#pragma unroll
      for (int qp = 0; qp < 4; ++qp) {
        bf16x8 pa0 = *(const bf16x8*)(smem + (2 * qp) * 16384 + ks * 1024 + lane16);
        bf16x8 pa1 = *(const bf16x8*)(smem + (2 * qp + 1) * 16384 + ks * 1024 + lane16);
        acc[0][2 * qp]     = __builtin_amdgcn_mfma_f32_16x16x32_bf16(pa0, v0, acc[0][2 * qp], 0, 0, 0);
        acc[1][2 * qp]     = __builtin_amdgcn_mfma_f32_16x16x32_bf16(pa0, v1, acc[1][2 * qp], 0, 0, 0);
        acc[2][2 * qp]     = __builtin_amdgcn_mfma_f32_16x16x32_bf16(pa0, v2, acc[2][2 * qp], 0, 0, 0);
        acc[3][2 * qp]     = __builtin_amdgcn_mfma_f32_16x16x32_bf16(pa0, v3, acc[3][2 * qp], 0, 0, 0);
        acc[0][2 * qp + 1] = __builtin_amdgcn_mfma_f32_16x16x32_bf16(pa1, v0, acc[0][2 * qp + 1], 0, 0, 0);
        acc[1][2 * qp + 1] = __builtin_amdgcn_mfma_f32_16x16x32_bf16(pa1, v1, acc[1][2 * qp + 1], 0, 0, 0);
        acc[2][2 * qp + 1] = __builtin_amdgcn_mfma_f32_16x16x32_bf16(pa1, v2, acc[2][2 * qp + 1], 0, 0, 0);
        acc[3][2 * qp + 1] = __builtin_amdgcn_mfma_f32_16x16x32_bf16(pa1, v3, acc[3][2 * qp + 1], 0, 0, 0);
      }
      __builtin_amdgcn_s_setprio(0);
    }
    float* outW = out + ((size_t)(b * 8192 + gs * 2048 + (q0 + 4 * h) * 4 + off)) * 1024
                  + dbase + l15;
#pragma unroll
    for (int cd = 0; cd < 4; ++cd)
#pragma unroll
      for (int qt = 0; qt < 8; ++qt)
#pragma unroll
        for (int r = 0; r < 4; ++r)
          outW[(size_t)((16 * qt + r) * 4) * 1024 + cd * 16] = acc[cd][qt][r];
  }
}

// ======================================================================
// ============ fallback path (round-4, verified PASS) ==================
#define KP_OFF 0
#define Q_OFF  65536
#define RED0   65536
#define RED1   67584
#define LDS_BYTES 73728

__global__ __launch_bounds__(256)
void vt_prepass(const float* __restrict__ x, uint16_t* __restrict__ vt) {
  __shared__ char tl[64 * 144];
  const int t    = threadIdx.x;
  const int blk  = blockIdx.x;
  const int dc   = blk & 15;
  const int kb   = (blk >> 4) & 7;
  const int prob = blk >> 7;
  const int b  = prob >> 4, off = (prob >> 2) & 3, gs = prob & 3;

  const int key = t >> 2, dq = t & 3;
  const float* src = x + ((size_t)(b * 8192 + gs * 2048 + (kb * 64 + key) * 4 + off)) * 1024
                     + dc * 64 + dq * 16;
  float4 f0 = *(const float4*)(src);
  float4 f1 = *(const float4*)(src + 4);
  float4 f2 = *(const float4*)(src + 8);
  float4 f3 = *(const float4*)(src + 12);
  const int swz = (key & 7) << 4;
  *(uint4*)(tl + key * 144 + ((dq * 32) ^ swz))      = pack8(f0, f1);
  *(uint4*)(tl + key * 144 + ((dq * 32 + 16) ^ swz)) = pack8(f2, f3);
  __syncthreads();
  const int d = t >> 2, kq = t & 3;
  uint32_t w[8];
#pragma unroll
  for (int i = 0; i < 8; ++i) {
    int k0 = kq * 16 + 2 * i, k1 = k0 + 1;
    uint32_t a  = *(const uint16_t*)(tl + k0 * 144 + ((2 * d) ^ ((k0 & 7) << 4)));
    uint32_t bb = *(const uint16_t*)(tl + k1 * 144 + ((2 * d) ^ ((k1 & 7) << 4)));
    w[i] = a | (bb << 16);
  }
  uint16_t* dst = vt + ((size_t)(prob * 1024 + dc * 64 + d)) * 512 + kb * 64 + kq * 16;
  *(uint4*)(dst)     = *(uint4*)&w[0];
  *(uint4*)(dst + 8) = *(uint4*)&w[4];
}

template <int USE_VT>
__global__ __launch_bounds__(512, 2)
void dilattn2(const float* __restrict__ x, const uint16_t* __restrict__ vt,
              float* __restrict__ out) {
  extern __shared__ char smem[];

  const int tid  = threadIdx.x;
  const int lane = tid & 63;
  const int wid  = tid >> 6;
  const int h    = lane >> 4;
  const int l15  = lane & 15;
  const int psw  = (l15 & 7) << 4;

  const int blk  = blockIdx.x;
  const int prob = blk >> 3;
  const int q0   = (blk & 7) * 64;
  const int b    = prob >> 4;
  const int off  = (prob >> 2) & 3;
  const int gs   = prob & 3;

  const float* xb = x + (size_t)b * (8192u * 1024u);

  const int srow = tid >> 3;
  const int sg   = tid & 7;
  const float* gK = xb + (size_t)(gs * 2048 + srow * 4 + off) * 1024 + sg * 8;
  const float* gQ = xb + (size_t)(gs * 2048 + (q0 + srow) * 4 + off) * 1024 + sg * 8;
  const int kWr = srow * 128 + ((sg * 16) ^ ((srow & 7) << 4));
  const int qWr = Q_OFF + kWr;

  const int akR = (64 * wid + l15) * 128;
  const int bqR = Q_OFF + l15 * 128;
  const int fb0 = (16 * h) ^ psw;

  f32x4 S[4][4];
#pragma unroll
  for (int i = 0; i < 4; ++i)
#pragma unroll
    for (int j = 0; j < 4; ++j) S[i][j] = (f32x4){0.f, 0.f, 0.f, 0.f};

  float4 kp[16], qp[2];
#pragma unroll
  for (int j = 0; j < 8; ++j) {
    const float* p = gK + (size_t)j * 262144;
    kp[2 * j]     = *(const float4*)(p);
    kp[2 * j + 1] = *(const float4*)(p + 4);
  }
  qp[0] = *(const float4*)(gQ);
  qp[1] = *(const float4*)(gQ + 4);

#pragma unroll 1
  for (int dc = 0; dc < 16; ++dc) {
#pragma unroll
    for (int j = 0; j < 8; ++j)
      *(uint4*)(smem + KP_OFF + kWr + j * 8192) = pack8(kp[2 * j], kp[2 * j + 1]);
    *(uint4*)(smem + qWr) = pack8(qp[0], qp[1]);
    if (dc < 15) {
      const int doff = (dc + 1) * 64;
#pragma unroll
      for (int j = 0; j < 8; ++j) {
        const float* p = gK + (size_t)j * 262144 + doff;
        kp[2 * j]     = *(const float4*)(p);
        kp[2 * j + 1] = *(const float4*)(p + 4);
      }
      qp[0] = *(const float4*)(gQ + doff);
      qp[1] = *(const float4*)(gQ + doff + 4);
    }
    __syncthreads();
#pragma unroll
    for (int s = 0; s < 2; ++s) {
      const int fb = fb0 ^ (s << 6);
      bf16x8 aK[4], bq[4];
#pragma unroll
      for (int kt = 0; kt < 4; ++kt)
        aK[kt] = *(const bf16x8*)(smem + akR + kt * 2048 + fb);
#pragma unroll
      for (int qt = 0; qt < 4; ++qt)
        bq[qt] = *(const bf16x8*)(smem + bqR + qt * 2048 + fb);
#pragma unroll
      for (int kt = 0; kt < 4; ++kt)
#pragma unroll
        for (int qt = 0; qt < 4; ++qt)
          S[kt][qt] = __builtin_amdgcn_mfma_f32_16x16x32_bf16(aK[kt], bq[qt], S[kt][qt], 0, 0, 0);
    }
    __syncthreads();
  }

  float mq[4], sq[4], rinv[4];
#pragma unroll
  for (int qt = 0; qt < 4; ++qt) {
    float m = S[0][qt][0];
#pragma unroll
    for (int kt = 0; kt < 4; ++kt)
#pragma unroll
      for (int r = 0; r < 4; ++r) m = fmaxf(m, S[kt][qt][r]);
    m = fmaxf(m, __shfl_xor(m, 16, 64));
    m = fmaxf(m, __shfl_xor(m, 32, 64));
    mq[qt] = m;
  }
  if (h == 0) {
#pragma unroll
    for (int qt = 0; qt < 4; ++qt)
      *(float*)(smem + RED0 + (wid * 64 + 16 * qt + l15) * 4) = mq[qt];
  }
  __syncthreads();
#pragma unroll
  for (int qt = 0; qt < 4; ++qt) {
    float m = -3e38f;
#pragma unroll
    for (int w = 0; w < 8; ++w)
      m = fmaxf(m, *(const float*)(smem + RED0 + (w * 64 + 16 * qt + l15) * 4));
    mq[qt] = m * SM_SCALE;
    sq[qt] = 0.f;
  }
#pragma unroll
  for (int kt = 0; kt < 4; ++kt)
#pragma unroll
    for (int qt = 0; qt < 4; ++qt)
#pragma unroll
      for (int r = 0; r < 4; ++r) {
        float v = exp2f((S[kt][qt][r] * SM_SCALE - mq[qt]) * LOG2E);
        S[kt][qt][r] = v;
        sq[qt] += v;
      }
#pragma unroll
  for (int qt = 0; qt < 4; ++qt) {
    sq[qt] += __shfl_xor(sq[qt], 16, 64);
    sq[qt] += __shfl_xor(sq[qt], 32, 64);
  }
  if (h == 0) {
#pragma unroll
    for (int qt = 0; qt < 4; ++qt)
      *(float*)(smem + RED1 + (wid * 64 + 16 * qt + l15) * 4) = sq[qt];
  }
  __syncthreads();
#pragma unroll
  for (int qt = 0; qt < 4; ++qt) {
    float l = 0.f;
#pragma unroll
    for (int w = 0; w < 8; ++w)
      l += *(const float*)(smem + RED1 + (w * 64 + 16 * qt + l15) * 4);
    rinv[qt] = 0.25f / l;
  }
#pragma unroll
  for (int kt = 0; kt < 4; ++kt)
#pragma unroll
    for (int qt = 0; qt < 4; ++qt) {
      uint2 w2;
      w2.x = pk2(S[kt][qt][0] * rinv[qt], S[kt][qt][1] * rinv[qt]);
      w2.y = pk2(S[kt][qt][2] * rinv[qt], S[kt][qt][3] * rinv[qt]);
      *(uint2*)(smem + KP_OFF + (16 * qt + l15) * 1024 +
                ((128 * wid + 32 * kt + 8 * h) ^ psw)) = w2;
    }
  __syncthreads();

  f32x4 acc[8][4];
#pragma unroll
  for (int i = 0; i < 8; ++i)
#pragma unroll
    for (int j = 0; j < 4; ++j) acc[i][j] = (f32x4){0.f, 0.f, 0.f, 0.f};

  const uint16_t* vtW = nullptr;
  if constexpr (USE_VT)
    vtW = vt + ((size_t)(prob * 1024 + 128 * wid + l15)) * 512 + 8 * h;

#pragma unroll 1
  for (int ks = 0; ks < 16; ++ks) {
    bf16x8 pa[4];
#pragma unroll
    for (int qt = 0; qt < 4; ++qt)
      pa[qt] = *(const bf16x8*)(smem + KP_OFF + (16 * qt + l15) * 1024 +
                                ((64 * ks + 16 * h) ^ psw));
#pragma unroll
    for (int cd = 0; cd < 8; ++cd) {
      bf16x8 v;
      if constexpr (USE_VT) {
        v = *(const bf16x8*)(vtW + (size_t)((cd >> 2) * 64 + (cd & 3) * 16) * 512 + 32 * ks);
      } else {
        const int d = 128 * wid + (cd >> 2) * 64 + (cd & 3) * 16 + l15;
        union { bf16x8 v; uint16_t u[8]; } a0;
#pragma unroll
        for (int jj = 0; jj < 8; ++jj) {
          int key = 32 * ks + 8 * h + jj;
          a0.u[jj] = (uint16_t)f2bf(xb[(size_t)(gs * 2048 + key * 4 + off) * 1024 + d]);
        }
        v = a0.v;
      }
#pragma unroll
      for (int qt = 0; qt < 4; ++qt)
        acc[cd][qt] = __builtin_amdgcn_mfma_f32_16x16x32_bf16(pa[qt], v, acc[cd][qt], 0, 0, 0);
    }
  }

#pragma unroll
  for (int cd = 0; cd < 8; ++cd) {
    const int d = 128 * wid + (cd >> 2) * 64 + (cd & 3) * 16 + l15;
#pragma unroll
    for (int qt = 0; qt < 4; ++qt)
#pragma unroll
      for (int r = 0; r < 4; ++r) {
        const int qq = q0 + 16 * qt + 4 * h + r;
        out[((size_t)(b * 8192 + gs * 2048 + qq * 4 + off)) * 1024 + d] = acc[cd][qt][r];
      }
  }
}

extern "C" void kernel_launch(void* const* d_in, const int* in_sizes, int n_in,
                              void* d_out, int out_size, void* d_ws, size_t ws_size,
                              hipStream_t stream) {
  const float* x = (const float*)d_in[0];
  float* out = (float*)d_out;
  (void)in_sizes; (void)n_in; (void)out_size;
  const size_t vt_bytes = 64ull * 1024 * 512 * 2;   // 64 MiB
  const size_t xf_bytes = 64ull * 1024 * 1024;      // 64 MiB
  if (ws_size >= vt_bytes + xf_bytes) {
    uint16_t* vtp = (uint16_t*)d_ws;
    uint16_t* xfp = (uint16_t*)((char*)d_ws + vt_bytes);
    hipFuncSetAttribute(reinterpret_cast<const void*>(dilattn12),
                        hipFuncAttributeMaxDynamicSharedMemorySize, LDSC_BYTES);
    prep_comb<<<8192, 256, 0, stream>>>(x, vtp, xfp);
    dilattn12<<<256, 512, LDSC_BYTES, stream>>>((const char*)xfp, (const char*)vtp, out);
  } else if (ws_size >= vt_bytes) {
    uint16_t* vtp = (uint16_t*)d_ws;
    hipFuncSetAttribute(reinterpret_cast<const void*>(dilattn2<1>),
                        hipFuncAttributeMaxDynamicSharedMemorySize, LDS_BYTES);
    vt_prepass<<<8192, 256, 0, stream>>>(x, vtp);
    dilattn2<1><<<512, 512, LDS_BYTES, stream>>>(x, vtp, out);
  } else {
    hipFuncSetAttribute(reinterpret_cast<const void*>(dilattn2<0>),
                        hipFuncAttributeMaxDynamicSharedMemorySize, LDS_BYTES);
    dilattn2<0><<<512, 512, LDS_BYTES, stream>>>(x, nullptr, out);
  }
}